// Round 3
// baseline (96.153 us; speedup 1.0000x reference)
//
#include <hip/hip_runtime.h>

typedef __attribute__((ext_vector_type(4))) float  f32x4;
typedef __attribute__((ext_vector_type(8))) __bf16 bf16x8;

// Chaining permutation. D-position q = mf*16 + g4*4 + r  (m = h index in D layout)
// B-position p = kk*32 + g4*8 + j                         (k = h index in B layout)
// Free register chaining: B_next[kk][j] = relu(acc[(kk<<1)|(j>>2)][j&3]) requires
// logical h at D-pos q to equal logical h at B-pos p under q=Q(p),
// Q(p) = ((kk<<1)|(j>>2))*16 + g4*4 + (j&3).  We store weight COLUMNS permuted by
// P = Q^{-1}:  P(q) = (q>>5)*32 + ((q>>2)&3)*8 + ((q>>4)&1)*4 + (q&3).
__device__ __forceinline__ int Pq(int q) {
  return ((q >> 5) << 5) + (((q >> 2) & 3) << 3) + (((q >> 4) & 1) << 2) + (q & 3);
}

// ---------------- setup: weights -> A-fragment order, columns permuted by P ----------
// A-frag (mfma_f32_16x16x32_bf16): lane(c,g4) elem j holds A[m=mf*16+c][k=kk*32+g4*8+j].
// A[q][p] = W[p][P(q)].  ws elem index = mat*4096 + (mf*2+kk)*512 + lane*8 + j.
__global__ void reformat_w(const float* __restrict__ h_wh,
                           const float* __restrict__ g_w1,
                           const float* __restrict__ g_wh,
                           __bf16* __restrict__ wsH,   // [2*64][4096]
                           __bf16* __restrict__ wsG)   // [3][4096]
{
  int i = blockIdx.x * 256 + threadIdx.x;
  int j = i & 7, lane = (i >> 3) & 63, f = (i >> 9) & 7;
  int c = lane & 15, g4 = lane >> 4, mf = f >> 1, kk = f & 1;
  int krow = (kk << 5) + (g4 << 3) + j;
  int mcol = Pq((mf << 4) + c);
  if (i < 524288) {                       // h: 2 layers * 64 heads * 4096
    int ld = i >> 12;
    wsH[i] = (__bf16)h_wh[(ld << 12) + (krow << 6) + mcol];
  } else if (i < 536576) {                // g: 3 matrices * 4096
    int t = i - 524288;
    int lg = t >> 12;
    const float* W = (lg == 0) ? g_w1 : g_wh + ((lg - 1) << 12);
    wsG[t] = (__bf16)W[(krow << 6) + mcol];
  }
}

// One MFMA layer: acc = A*B + bias; optionally rebuild B-frags from acc (relu+cvt,
// pure register renaming thanks to the P-permuted weights).
__device__ __forceinline__ void layer(const __bf16* __restrict__ wf,
                                      const float* __restrict__ bias,
                                      int lane, int g4, bool rebuild,
                                      f32x4 (&acc)[4][4], bf16x8 (&bfr)[4][2])
{
  bf16x8 aw0[4], aw1[4];
  #pragma unroll
  for (int mf = 0; mf < 4; ++mf) {
    aw0[mf] = *(const bf16x8*)&wf[((mf << 1) << 9) + (lane << 3)];
    aw1[mf] = *(const bf16x8*)&wf[(((mf << 1) | 1) << 9) + (lane << 3)];
  }
  f32x4 bv[4];
  #pragma unroll
  for (int mf = 0; mf < 4; ++mf)   // bias at D-pos q: bias[P(q)], contiguous x4
    bv[mf] = *(const f32x4*)&bias[((mf >> 1) << 5) + (g4 << 3) + ((mf & 1) << 2)];
  #pragma unroll
  for (int mf = 0; mf < 4; ++mf)
    #pragma unroll
    for (int nf = 0; nf < 4; ++nf)
      acc[mf][nf] = __builtin_amdgcn_mfma_f32_16x16x32_bf16(aw0[mf], bfr[nf][0], bv[mf], 0, 0, 0);
  #pragma unroll
  for (int mf = 0; mf < 4; ++mf)
    #pragma unroll
    for (int nf = 0; nf < 4; ++nf)
      acc[mf][nf] = __builtin_amdgcn_mfma_f32_16x16x32_bf16(aw1[mf], bfr[nf][1], acc[mf][nf], 0, 0, 0);
  if (rebuild) {
    #pragma unroll
    for (int nf = 0; nf < 4; ++nf)
      #pragma unroll
      for (int kk = 0; kk < 2; ++kk) {
        bf16x8 v;
        #pragma unroll
        for (int e = 0; e < 8; ++e)
          v[e] = (__bf16)fmaxf(acc[(kk << 1) | (e >> 2)][nf][e & 3], 0.f);
        bfr[nf][kk] = v;
      }
  }
}

__global__ __launch_bounds__(256, 4) void fused_nn(
    const float* __restrict__ x,
    const float* __restrict__ h_w1, const float* __restrict__ h_b1,
    const float* __restrict__ h_bh,
    const float* __restrict__ h_wo, const float* __restrict__ h_bo,
    const float* __restrict__ g_b1, const float* __restrict__ g_bh,
    const float* __restrict__ g_wo, const float* __restrict__ g_bo,
    const __bf16* __restrict__ wsH, const __bf16* __restrict__ wsG,
    float* __restrict__ out, int Btot)
{
  const int tid  = threadIdx.x;
  const int lane = tid & 63;
  const int wid  = tid >> 6;
  const int c    = lane & 15;
  const int g4   = lane >> 4;

  const int bid  = blockIdx.x;
  const int tile = bid / 65;             // tile-major: the 65 blocks of a tile are adjacent
  const int sub  = bid - tile * 65;
  const bool is_h = (sub < 64);
  const int d    = sub & 63;
  const int nb   = (tile << 8) + (wid << 6);   // wave's 64-batch base

  f32x4  acc[4][4];
  bf16x8 bfr[4][2];

  if (is_h) {
    // ---- h1 = relu(s * w1 + b1), built directly as B-fragments (identity positions) ----
    const float* w1p = h_w1 + (d << 6);
    const float* b1p = h_b1 + (d << 6);
    f32x4 w1v[2][2], b1v[2][2];
    #pragma unroll
    for (int kk = 0; kk < 2; ++kk)
      #pragma unroll
      for (int h = 0; h < 2; ++h) {
        int off = (kk << 5) + (g4 << 3) + (h << 2);
        w1v[kk][h] = *(const f32x4*)&w1p[off];
        b1v[kk][h] = *(const f32x4*)&b1p[off];
      }
    #pragma unroll
    for (int nf = 0; nf < 4; ++nf) {
      float s = x[(size_t)(nb + (nf << 4) + c) * 128 + 64 + d];
      #pragma unroll
      for (int kk = 0; kk < 2; ++kk) {
        bf16x8 v;
        #pragma unroll
        for (int h = 0; h < 2; ++h)
          #pragma unroll
          for (int r = 0; r < 4; ++r)
            v[(h << 2) + r] = (__bf16)fmaxf(fmaf(s, w1v[kk][h][r], b1v[kk][h][r]), 0.f);
        bfr[nf][kk] = v;
      }
    }
    layer(wsH + (d << 12),        h_bh + (d << 6),        lane, g4, true,  acc, bfr);
    layer(wsH + ((64 + d) << 12), h_bh + ((64 + d) << 6), lane, g4, false, acc, bfr);
  } else {
    // ---- g layer-1 input: x[:, :64] as B-fragments (identity positions) ----
    #pragma unroll
    for (int nf = 0; nf < 4; ++nf) {
      const float* xr = x + (size_t)(nb + (nf << 4) + c) * 128;
      #pragma unroll
      for (int kk = 0; kk < 2; ++kk) {
        f32x4 v0 = *(const f32x4*)&xr[(kk << 5) + (g4 << 3)];
        f32x4 v1 = *(const f32x4*)&xr[(kk << 5) + (g4 << 3) + 4];
        bf16x8 v;
        #pragma unroll
        for (int r = 0; r < 4; ++r) { v[r] = (__bf16)v0[r]; v[4 + r] = (__bf16)v1[r]; }
        bfr[nf][kk] = v;
      }
    }
    layer(wsG,        g_b1,      lane, g4, true,  acc, bfr);
    layer(wsG + 4096, g_bh,      lane, g4, true,  acc, bfr);
    layer(wsG + 8192, g_bh + 64, lane, g4, false, acc, bfr);
  }

  // ---- epilogue: relu -> dot(wo[P(q)]) -> reduce over g4 groups ----
  const float* wo = is_h ? h_wo + (d << 6) : g_wo;
  const float  ob = is_h ? h_bo[d] : g_bo[0];
  f32x4 wv[4];
  #pragma unroll
  for (int mf = 0; mf < 4; ++mf)
    wv[mf] = *(const f32x4*)&wo[((mf >> 1) << 5) + (g4 << 3) + ((mf & 1) << 2)];
  float p[4] = {0.f, 0.f, 0.f, 0.f};
  #pragma unroll
  for (int mf = 0; mf < 4; ++mf)
    #pragma unroll
    for (int nf = 0; nf < 4; ++nf)
      #pragma unroll
      for (int r = 0; r < 4; ++r)
        p[nf] += fmaxf(acc[mf][nf][r], 0.f) * wv[mf][r];
  #pragma unroll
  for (int nf = 0; nf < 4; ++nf) {
    p[nf] += __shfl_xor(p[nf], 16);
    p[nf] += __shfl_xor(p[nf], 32);
  }
  float sel = (g4 == 0) ? p[0] : (g4 == 1) ? p[1] : (g4 == 2) ? p[2] : p[3];
  int batch = nb + lane;
  if (is_h) out[((size_t)batch << 6) + d]   = sel + ob;
  else      out[((size_t)Btot << 6) + batch] = sel + ob;
}

extern "C" void kernel_launch(void* const* d_in, const int* in_sizes, int n_in,
                              void* d_out, int out_size, void* d_ws, size_t ws_size,
                              hipStream_t stream) {
  const float* x    = (const float*)d_in[0];
  const float* h_w1 = (const float*)d_in[1];
  const float* h_b1 = (const float*)d_in[2];
  const float* h_wh = (const float*)d_in[3];
  const float* h_bh = (const float*)d_in[4];
  const float* h_wo = (const float*)d_in[5];
  const float* h_bo = (const float*)d_in[6];
  const float* g_w1 = (const float*)d_in[7];
  const float* g_b1 = (const float*)d_in[8];
  const float* g_wh = (const float*)d_in[9];
  const float* g_bh = (const float*)d_in[10];
  const float* g_wo = (const float*)d_in[11];
  const float* g_bo = (const float*)d_in[12];

  __bf16* wsH = (__bf16*)d_ws;                               // 2*64*4096 bf16 = 1 MB
  __bf16* wsG = (__bf16*)((char*)d_ws + 2 * 64 * 4096 * 2);  // 3*4096 bf16 = 24 KB

  const int Btot   = in_sizes[0] / 128;   // 32768
  const int nTiles = Btot >> 8;           // 128

  hipLaunchKernelGGL(reformat_w, dim3(2096), dim3(256), 0, stream,
                     h_wh, g_w1, g_wh, wsH, wsG);

  hipLaunchKernelGGL(fused_nn, dim3(nTiles * 65), dim3(256), 0, stream,
                     x, h_w1, h_b1, h_bh, h_wo, h_bo,
                     g_b1, g_bh, g_wo, g_bo,
                     (const __bf16*)wsH, (const __bf16*)wsG,
                     (float*)d_out, Btot);
}